// Round 1
// baseline (1036.087 us; speedup 1.0000x reference)
//
#include <hip/hip_runtime.h>
#include <stdint.h>

typedef unsigned short u16;
typedef __attribute__((ext_vector_type(8))) short short8;
typedef __attribute__((ext_vector_type(4))) float f32x4;

#define BB 4
#define TT 1024
#define CC 1024
#define HH 16
#define NN 64
#define MM (BB*TT)        // 4096 rows
#define FFN_ 4096
static constexpr float EPS_ = 1e-5f;

__device__ __forceinline__ u16 f2bf(float f) {
    union { float f; uint32_t u; } x; x.f = f;
    uint32_t r = x.u + 0x7fff + ((x.u >> 16) & 1);   // RNE
    return (u16)(r >> 16);
}

// ---------------- LayerNorm (row = b*T + t, C=1024) ----------------
__global__ __launch_bounds__(256) void ln_kernel(const float* __restrict__ x,
    const float* __restrict__ w, const float* __restrict__ b, float* __restrict__ out)
{
    int row = blockIdx.x;
    int tid = threadIdx.x;
    const float* xr = x + (size_t)row * CC;
    float4 v = ((const float4*)xr)[tid];
    float s  = v.x + v.y + v.z + v.w;
    float ss = v.x*v.x + v.y*v.y + v.z*v.z + v.w*v.w;
#pragma unroll
    for (int m = 1; m < 64; m <<= 1) { s += __shfl_xor(s, m); ss += __shfl_xor(ss, m); }
    __shared__ float as_[4], bs_[4];
    int wv = tid >> 6, ln = tid & 63;
    if (ln == 0) { as_[wv] = s; bs_[wv] = ss; }
    __syncthreads();
    s  = as_[0] + as_[1] + as_[2] + as_[3];
    ss = bs_[0] + bs_[1] + bs_[2] + bs_[3];
    float mean = s * (1.f / CC);
    float var  = ss * (1.f / CC) - mean * mean;
    float inv  = rsqrtf(var + EPS_);
    float4 w4 = ((const float4*)w)[tid];
    float4 b4 = ((const float4*)b)[tid];
    float4 o;
    o.x = (v.x - mean) * inv * w4.x + b4.x;
    o.y = (v.y - mean) * inv * w4.y + b4.y;
    o.z = (v.z - mean) * inv * w4.z + b4.z;
    o.w = (v.w - mean) * inv * w4.w + b4.w;
    ((float4*)(out + (size_t)row * CC))[tid] = o;
}

// ---------------- time-mix combine (4 outputs, bf16) ----------------
__global__ __launch_bounds__(256) void mix1_kernel(const float* __restrict__ xln,
    const float* __restrict__ mk, const float* __restrict__ mv,
    const float* __restrict__ mr, const float* __restrict__ mg,
    u16* __restrict__ xk, u16* __restrict__ xv, u16* __restrict__ xr, u16* __restrict__ xg)
{
    int i4 = blockIdx.x * 256 + threadIdx.x;   // one float4 per thread, 1M total
    int f = i4 << 2;
    int c = f & (CC - 1);
    int t = (f >> 10) & (TT - 1);
    float4 xc = *(const float4*)(xln + f);
    float4 xp = make_float4(0.f, 0.f, 0.f, 0.f);
    if (t) xp = *(const float4*)(xln + f - CC);
    float4 k4 = *(const float4*)(mk + c);
    float4 v4 = *(const float4*)(mv + c);
    float4 r4 = *(const float4*)(mr + c);
    float4 g4 = *(const float4*)(mg + c);
    ushort4 ok, ov, orr, og;
    ok.x  = f2bf(xp.x + k4.x * (xc.x - xp.x)); ok.y  = f2bf(xp.y + k4.y * (xc.y - xp.y));
    ok.z  = f2bf(xp.z + k4.z * (xc.z - xp.z)); ok.w  = f2bf(xp.w + k4.w * (xc.w - xp.w));
    ov.x  = f2bf(xp.x + v4.x * (xc.x - xp.x)); ov.y  = f2bf(xp.y + v4.y * (xc.y - xp.y));
    ov.z  = f2bf(xp.z + v4.z * (xc.z - xp.z)); ov.w  = f2bf(xp.w + v4.w * (xc.w - xp.w));
    orr.x = f2bf(xp.x + r4.x * (xc.x - xp.x)); orr.y = f2bf(xp.y + r4.y * (xc.y - xp.y));
    orr.z = f2bf(xp.z + r4.z * (xc.z - xp.z)); orr.w = f2bf(xp.w + r4.w * (xc.w - xp.w));
    og.x  = f2bf(xp.x + g4.x * (xc.x - xp.x)); og.y  = f2bf(xp.y + g4.y * (xc.y - xp.y));
    og.z  = f2bf(xp.z + g4.z * (xc.z - xp.z)); og.w  = f2bf(xp.w + g4.w * (xc.w - xp.w));
    *(ushort4*)(xk + f) = ok;
    *(ushort4*)(xv + f) = ov;
    *(ushort4*)(xr + f) = orr;
    *(ushort4*)(xg + f) = og;
}

// ---------------- channel-mix combine (2 outputs, bf16) ----------------
__global__ __launch_bounds__(256) void mix2_kernel(const float* __restrict__ xln,
    const float* __restrict__ mk, const float* __restrict__ mr,
    u16* __restrict__ xk, u16* __restrict__ xr)
{
    int i4 = blockIdx.x * 256 + threadIdx.x;
    int f = i4 << 2;
    int c = f & (CC - 1);
    int t = (f >> 10) & (TT - 1);
    float4 xc = *(const float4*)(xln + f);
    float4 xp = make_float4(0.f, 0.f, 0.f, 0.f);
    if (t) xp = *(const float4*)(xln + f - CC);
    float4 k4 = *(const float4*)(mk + c);
    float4 r4 = *(const float4*)(mr + c);
    ushort4 ok, orr;
    ok.x  = f2bf(xp.x + k4.x * (xc.x - xp.x)); ok.y  = f2bf(xp.y + k4.y * (xc.y - xp.y));
    ok.z  = f2bf(xp.z + k4.z * (xc.z - xp.z)); ok.w  = f2bf(xp.w + k4.w * (xc.w - xp.w));
    orr.x = f2bf(xp.x + r4.x * (xc.x - xp.x)); orr.y = f2bf(xp.y + r4.y * (xc.y - xp.y));
    orr.z = f2bf(xp.z + r4.z * (xc.z - xp.z)); orr.w = f2bf(xp.w + r4.w * (xc.w - xp.w));
    *(ushort4*)(xk + f) = ok;
    *(ushort4*)(xr + f) = orr;
}

// ---------------- fp32 -> bf16 weight conversion (all weights, one kernel) ----------------
struct ConvArgs {
    const float* src[8];
    u16* dst[8];
    int start4[8];   // prefix starts in float4 units
};
__global__ __launch_bounds__(256) void conv_kernel(ConvArgs a, int total4)
{
    int i4 = blockIdx.x * 256 + threadIdx.x;
    if (i4 >= total4) return;
    int s = 0;
#pragma unroll
    for (int j = 1; j < 8; ++j) if (i4 >= a.start4[j]) s = j;
    int l4 = i4 - a.start4[s];
    float4 v = ((const float4*)a.src[s])[l4];
    ushort4 o; o.x = f2bf(v.x); o.y = f2bf(v.y); o.z = f2bf(v.z); o.w = f2bf(v.w);
    ((ushort4*)a.dst[s])[l4] = o;
}

// ---------------- bf16 MFMA GEMM: Y(M,N) = A(M,K) @ Bw(N,K)^T, m97-style ----------------
// EPI: 0 plain f32 | 1 silu f32 | 2 aux1+v f32 | 3 relu(v)^2 -> bf16 | 4 sigmoid f32 | 5 aux1+aux2*v f32
template<int EPI>
__global__ __launch_bounds__(256) void gemm_bt(
    const u16* __restrict__ A, const u16* __restrict__ Bw,
    float* __restrict__ Cf, u16* __restrict__ Cbf,
    const float* __restrict__ aux1, const float* __restrict__ aux2,
    int Mdim, int Ndim, int Kdim)
{
    __shared__ u16 As[128 * 32];
    __shared__ u16 Bs[128 * 32];
    int tid = threadIdx.x;
    int w = tid >> 6, lane = tid & 63;
    int bx = blockIdx.x, by = blockIdx.y;
    int rowBase = by * 128, colBase = bx * 128;
    int wr = w >> 1, wc = w & 1;
    int fr = lane & 15, fk = (lane >> 4) * 8;

    f32x4 acc[4][4] = {};

    int nK = Kdim >> 5;
    for (int kt = 0; kt < nK; ++kt) {
        int k0 = kt << 5;
#pragma unroll
        for (int q = 0; q < 2; ++q) {
            int c = w * 128 + q * 64 + lane;          // chunk id 0..511, 16B each
            const u16* ga = A + (size_t)(rowBase + (c >> 2)) * Kdim + k0 + ((c & 3) << 3);
            __builtin_amdgcn_global_load_lds(
                (const __attribute__((address_space(1))) uint32_t*)(const void*)ga,
                (__attribute__((address_space(3))) uint32_t*)(void*)(As + (size_t)(w * 128 + q * 64) * 8),
                16, 0, 0);
            const u16* gb = Bw + (size_t)(colBase + (c >> 2)) * Kdim + k0 + ((c & 3) << 3);
            __builtin_amdgcn_global_load_lds(
                (const __attribute__((address_space(1))) uint32_t*)(const void*)gb,
                (__attribute__((address_space(3))) uint32_t*)(void*)(Bs + (size_t)(w * 128 + q * 64) * 8),
                16, 0, 0);
        }
        __syncthreads();
        short8 af[4], bf[4];
#pragma unroll
        for (int m = 0; m < 4; ++m)
            af[m] = *(const short8*)&As[(wr * 64 + m * 16 + fr) * 32 + fk];
#pragma unroll
        for (int n = 0; n < 4; ++n)
            bf[n] = *(const short8*)&Bs[(wc * 64 + n * 16 + fr) * 32 + fk];
#pragma unroll
        for (int m = 0; m < 4; ++m)
#pragma unroll
            for (int n = 0; n < 4; ++n)
                acc[m][n] = __builtin_amdgcn_mfma_f32_16x16x32_bf16(af[m], bf[n], acc[m][n], 0, 0, 0);
        __syncthreads();
    }

    int r0 = rowBase + wr * 64, c0 = colBase + wc * 64;
#pragma unroll
    for (int m = 0; m < 4; ++m) {
#pragma unroll
        for (int n = 0; n < 4; ++n) {
#pragma unroll
            for (int rg = 0; rg < 4; ++rg) {
                int gr = r0 + m * 16 + (lane >> 4) * 4 + rg;
                int gc = c0 + n * 16 + (lane & 15);
                size_t idx = (size_t)gr * Ndim + gc;
                float v = acc[m][n][rg];
                if (EPI == 0) Cf[idx] = v;
                else if (EPI == 1) Cf[idx] = v / (1.f + __expf(-v));
                else if (EPI == 2) Cf[idx] = aux1[idx] + v;
                else if (EPI == 3) { float rr = v > 0.f ? v : 0.f; Cbf[idx] = f2bf(rr * rr); }
                else if (EPI == 4) Cf[idx] = 1.f / (1.f + __expf(-v));
                else Cf[idx] = aux1[idx] + aux2[idx] * v;
            }
        }
    }
}

// ---------------- WKV5 scan ----------------
// grid: B*H*4 blocks of 64 threads. Block handles 16 columns j (jb*16..+15).
// lane = g*16+jj: g = i-group (16 states), jj = local column.
__global__ __launch_bounds__(64) void wkv5_kernel(
    const float* __restrict__ r, const float* __restrict__ k, const float* __restrict__ v,
    const float* __restrict__ decay, const float* __restrict__ u, float* __restrict__ y)
{
    int blk = blockIdx.x;
    int jb = blk & 3, h = (blk >> 2) & (HH - 1), b = blk >> 6;
    int lane = threadIdx.x;
    int jj = lane & 15, g = lane >> 4;
    __shared__ float rkbuf[128];
    float S[16], uu[16], ew[16];
#pragma unroll
    for (int ii = 0; ii < 16; ++ii) {
        int i = g * 16 + ii;
        S[ii] = 0.f;
        float wv = decay[h * NN + i];
        ew[ii] = expf(-expf(wv));
        uu[ii] = u[h * NN + i];
    }
    const size_t base = ((size_t)b * TT) * CC + h * NN;
    const float* rb = r + base;
    const float* kb = k + base;
    const float* vb = v + base + jb * 16;
    float* yb = y + base + jb * 16;

    for (int t = 0; t < TT; ++t) {
        size_t off = (size_t)t * CC;
        float rv  = rb[off + lane];
        float kv_ = kb[off + lane];
        float vv  = vb[off + jj];
        rkbuf[2 * lane]     = rv;
        rkbuf[2 * lane + 1] = kv_;
        __syncthreads();
        float acc = 0.f;
        const float2* rk2 = (const float2*)rkbuf;
#pragma unroll
        for (int ii = 0; ii < 16; ++ii) {
            float2 p = rk2[g * 16 + ii];
            float kvv = p.y * vv;
            float t1 = fmaf(uu[ii], kvv, S[ii]);      // S_old + u*k*v
            acc = fmaf(p.x, t1, acc);
            S[ii] = fmaf(ew[ii], S[ii], kvv);         // S = ew*S + k*v
        }
        acc += __shfl_xor(acc, 16);
        acc += __shfl_xor(acc, 32);
        if (g == 0) yb[off + jj] = acc;
        __syncthreads();
    }
}

// ---------------- GroupNorm(y/8)*w+b, multiply by silu(g), -> bf16 ----------------
__global__ __launch_bounds__(256) void gn_kernel(const float* __restrict__ y,
    const float* __restrict__ gsilu, const float* __restrict__ w, const float* __restrict__ b,
    u16* __restrict__ og)
{
    int row = blockIdx.x;          // b*T + t
    int tid = threadIdx.x;
    int head = tid >> 4, q = tid & 15;
    size_t base = (size_t)row * CC + head * NN + q * 4;
    float4 v = *(const float4*)(y + base);
    v.x *= 0.125f; v.y *= 0.125f; v.z *= 0.125f; v.w *= 0.125f;
    float s  = v.x + v.y + v.z + v.w;
    float ss = v.x*v.x + v.y*v.y + v.z*v.z + v.w*v.w;
#pragma unroll
    for (int m = 1; m < 16; m <<= 1) { s += __shfl_xor(s, m); ss += __shfl_xor(ss, m); }
    float mean = s * (1.f / NN);
    float var  = ss * (1.f / NN) - mean * mean;
    float inv  = rsqrtf(var + EPS_);
    int cb = head * NN + q * 4;
    float4 w4 = *(const float4*)(w + cb);
    float4 b4 = *(const float4*)(b + cb);
    float4 g4 = *(const float4*)(gsilu + base);
    ushort4 o;
    o.x = f2bf(((v.x - mean) * inv * w4.x + b4.x) * g4.x);
    o.y = f2bf(((v.y - mean) * inv * w4.y + b4.y) * g4.y);
    o.z = f2bf(((v.z - mean) * inv * w4.z + b4.z) * g4.z);
    o.w = f2bf(((v.w - mean) * inv * w4.w + b4.w) * g4.w);
    *(ushort4*)(og + base) = o;
}

// ---------------- launcher ----------------
extern "C" void kernel_launch(void* const* d_in, const int* in_sizes, int n_in,
                              void* d_out, int out_size, void* d_ws, size_t ws_size,
                              hipStream_t stream)
{
    const float* x       = (const float*)d_in[0];
    const float* ln1_w   = (const float*)d_in[1];
    const float* ln1_b   = (const float*)d_in[2];
    const float* ln2_w   = (const float*)d_in[3];
    const float* ln2_b   = (const float*)d_in[4];
    const float* tm_mix_k= (const float*)d_in[5];
    const float* tm_mix_v= (const float*)d_in[6];
    const float* tm_mix_r= (const float*)d_in[7];
    const float* tm_mix_g= (const float*)d_in[8];
    const float* tm_decay= (const float*)d_in[9];
    const float* tm_u    = (const float*)d_in[10];
    const float* Wr      = (const float*)d_in[11];
    const float* Wk      = (const float*)d_in[12];
    const float* Wv      = (const float*)d_in[13];
    const float* Wg      = (const float*)d_in[14];
    const float* Wo      = (const float*)d_in[15];
    const float* lnx_w   = (const float*)d_in[16];
    const float* lnx_b   = (const float*)d_in[17];
    const float* cm_mix_k= (const float*)d_in[18];
    const float* cm_mix_r= (const float*)d_in[19];
    const float* cm_Wk   = (const float*)d_in[20];
    const float* cm_Wr   = (const float*)d_in[21];
    const float* cm_Wv   = (const float*)d_in[22];

    char* ws = (char*)d_ws;
    auto MB = [](size_t m) { return m * 1024ull * 1024ull; };
    float* xln    = (float*)(ws + 0);         // 16MB (reused for ln2)
    u16*   xk     = (u16*)(ws + MB(16));      // 8MB (reused for cm xk)
    u16*   xv     = (u16*)(ws + MB(24));      // 8MB
    u16*   xr     = (u16*)(ws + MB(32));      // 8MB (reused for cm xr)
    u16*   xg     = (u16*)(ws + MB(40));      // 8MB
    float* rbuf   = (float*)(ws + MB(48));    // 16MB
    float* kbuf_f = (float*)(ws + MB(64));    // 16MB
    float* vbuf   = (float*)(ws + MB(80));    // 16MB
    float* gbuf   = (float*)(ws + MB(96));    // 16MB (silu g; reused for sr)
    float* ybuf   = (float*)(ws + MB(112));   // 16MB
    u16*   og     = (u16*)(ws + MB(128));     // 8MB
    float* x1     = (float*)(ws + MB(136));   // 16MB
    u16*   kbuf2  = (u16*)(ws + MB(48));      // 32MB bf16 (B,T,FFN), overlaps r/k (dead by then)
    u16*   wbf    = (u16*)(ws + MB(152));     // bf16 weights, 30MB total
    u16* Wr_b   = wbf;
    u16* Wk_b   = wbf + (1u << 20) * 1;
    u16* Wv_b   = wbf + (1u << 20) * 2;
    u16* Wg_b   = wbf + (1u << 20) * 3;
    u16* Wo_b   = wbf + (1u << 20) * 4;
    u16* cmWk_b = wbf + (1u << 20) * 5;       // 4M elems
    u16* cmWr_b = cmWk_b + (4u << 20);
    u16* cmWv_b = cmWr_b + (1u << 20);        // 4M elems

    // 1. weights fp32 -> bf16
    ConvArgs ca;
    ca.src[0] = Wr;    ca.dst[0] = Wr_b;
    ca.src[1] = Wk;    ca.dst[1] = Wk_b;
    ca.src[2] = Wv;    ca.dst[2] = Wv_b;
    ca.src[3] = Wg;    ca.dst[3] = Wg_b;
    ca.src[4] = Wo;    ca.dst[4] = Wo_b;
    ca.src[5] = cm_Wk; ca.dst[5] = cmWk_b;
    ca.src[6] = cm_Wr; ca.dst[6] = cmWr_b;
    ca.src[7] = cm_Wv; ca.dst[7] = cmWv_b;
    int q = (CC * CC) / 4;   // 262144
    int st[8] = {0, q, 2*q, 3*q, 4*q, 5*q, 5*q + 4*q, 5*q + 4*q + q};
    for (int i = 0; i < 8; ++i) ca.start4[i] = st[i];
    int total4 = 5*q + 4*q + q + 4*q;  // 14*q = 3,670,016
    conv_kernel<<<(total4 + 255) / 256, 256, 0, stream>>>(ca, total4);

    // 2. LN1 + time-mix
    ln_kernel<<<MM, 256, 0, stream>>>(x, ln1_w, ln1_b, xln);
    mix1_kernel<<<(MM * CC / 4) / 256, 256, 0, stream>>>(xln, tm_mix_k, tm_mix_v, tm_mix_r, tm_mix_g,
                                                         xk, xv, xr, xg);
    // 3. r,k,v,g projections
    dim3 g1(CC / 128, MM / 128);
    gemm_bt<0><<<g1, 256, 0, stream>>>(xr, Wr_b, rbuf,   nullptr, nullptr, nullptr, MM, CC, CC);
    gemm_bt<0><<<g1, 256, 0, stream>>>(xk, Wk_b, kbuf_f, nullptr, nullptr, nullptr, MM, CC, CC);
    gemm_bt<0><<<g1, 256, 0, stream>>>(xv, Wv_b, vbuf,   nullptr, nullptr, nullptr, MM, CC, CC);
    gemm_bt<1><<<g1, 256, 0, stream>>>(xg, Wg_b, gbuf,   nullptr, nullptr, nullptr, MM, CC, CC);

    // 4. WKV5 recurrence
    wkv5_kernel<<<BB * HH * 4, 64, 0, stream>>>(rbuf, kbuf_f, vbuf, tm_decay, tm_u, ybuf);

    // 5. GroupNorm(y/8) * g -> bf16
    gn_kernel<<<MM, 256, 0, stream>>>(ybuf, gbuf, lnx_w, lnx_b, og);

    // 6. x1 = x + og @ Wo^T
    gemm_bt<2><<<g1, 256, 0, stream>>>(og, Wo_b, x1, nullptr, x, nullptr, MM, CC, CC);

    // 7. LN2 + channel-mix
    ln_kernel<<<MM, 256, 0, stream>>>(x1, ln2_w, ln2_b, xln);
    mix2_kernel<<<(MM * CC / 4) / 256, 256, 0, stream>>>(xln, cm_mix_k, cm_mix_r, xk, xr);

    // 8. kbuf = relu(xk @ cm_Wk^T)^2 (bf16); sr = sigmoid(xr @ cm_Wr^T)
    dim3 g6(FFN_ / 128, MM / 128);
    gemm_bt<3><<<g6, 256, 0, stream>>>(xk, cmWk_b, nullptr, kbuf2, nullptr, nullptr, MM, FFN_, CC);
    gemm_bt<4><<<g1, 256, 0, stream>>>(xr, cmWr_b, gbuf, nullptr, nullptr, nullptr, MM, CC, CC);

    // 9. out = x1 + sr * (kbuf @ cm_Wv^T)
    gemm_bt<5><<<g1, 256, 0, stream>>>(kbuf2, cmWv_b, (float*)d_out, nullptr, x1, gbuf, MM, CC, FFN_);
}

// Round 2
// 584.221 us; speedup vs baseline: 1.7734x; 1.7734x over previous
//
#include <hip/hip_runtime.h>
#include <stdint.h>

typedef unsigned short u16;
typedef __attribute__((ext_vector_type(8))) short short8;
typedef __attribute__((ext_vector_type(4))) float f32x4;

#define BB 4
#define TT 1024
#define CC 1024
#define HH 16
#define NN 64
#define MM (BB*TT)        // 4096 rows
#define FFN_ 4096
#define PCH 16            // WKV chunks
#define LCH (TT/PCH)      // 64 steps per chunk
static constexpr float EPS_ = 1e-5f;

__device__ __forceinline__ u16 f2bf(float f) {
    union { float f; uint32_t u; } x; x.f = f;
    uint32_t r = x.u + 0x7fff + ((x.u >> 16) & 1);   // RNE
    return (u16)(r >> 16);
}

// ---------------- LayerNorm (row = b*T + t, C=1024) ----------------
__global__ __launch_bounds__(256) void ln_kernel(const float* __restrict__ x,
    const float* __restrict__ w, const float* __restrict__ b, float* __restrict__ out)
{
    int row = blockIdx.x;
    int tid = threadIdx.x;
    const float* xr = x + (size_t)row * CC;
    float4 v = ((const float4*)xr)[tid];
    float s  = v.x + v.y + v.z + v.w;
    float ss = v.x*v.x + v.y*v.y + v.z*v.z + v.w*v.w;
#pragma unroll
    for (int m = 1; m < 64; m <<= 1) { s += __shfl_xor(s, m); ss += __shfl_xor(ss, m); }
    __shared__ float as_[4], bs_[4];
    int wv = tid >> 6, ln = tid & 63;
    if (ln == 0) { as_[wv] = s; bs_[wv] = ss; }
    __syncthreads();
    s  = as_[0] + as_[1] + as_[2] + as_[3];
    ss = bs_[0] + bs_[1] + bs_[2] + bs_[3];
    float mean = s * (1.f / CC);
    float var  = ss * (1.f / CC) - mean * mean;
    float inv  = rsqrtf(var + EPS_);
    float4 w4 = ((const float4*)w)[tid];
    float4 b4 = ((const float4*)b)[tid];
    float4 o;
    o.x = (v.x - mean) * inv * w4.x + b4.x;
    o.y = (v.y - mean) * inv * w4.y + b4.y;
    o.z = (v.z - mean) * inv * w4.z + b4.z;
    o.w = (v.w - mean) * inv * w4.w + b4.w;
    ((float4*)(out + (size_t)row * CC))[tid] = o;
}

// ---------------- time-mix combine (4 outputs, bf16) ----------------
__global__ __launch_bounds__(256) void mix1_kernel(const float* __restrict__ xln,
    const float* __restrict__ mk, const float* __restrict__ mv,
    const float* __restrict__ mr, const float* __restrict__ mg,
    u16* __restrict__ xk, u16* __restrict__ xv, u16* __restrict__ xr, u16* __restrict__ xg)
{
    int i4 = blockIdx.x * 256 + threadIdx.x;   // one float4 per thread, 1M total
    int f = i4 << 2;
    int c = f & (CC - 1);
    int t = (f >> 10) & (TT - 1);
    float4 xc = *(const float4*)(xln + f);
    float4 xp = make_float4(0.f, 0.f, 0.f, 0.f);
    if (t) xp = *(const float4*)(xln + f - CC);
    float4 k4 = *(const float4*)(mk + c);
    float4 v4 = *(const float4*)(mv + c);
    float4 r4 = *(const float4*)(mr + c);
    float4 g4 = *(const float4*)(mg + c);
    ushort4 ok, ov, orr, og;
    ok.x  = f2bf(xp.x + k4.x * (xc.x - xp.x)); ok.y  = f2bf(xp.y + k4.y * (xc.y - xp.y));
    ok.z  = f2bf(xp.z + k4.z * (xc.z - xp.z)); ok.w  = f2bf(xp.w + k4.w * (xc.w - xp.w));
    ov.x  = f2bf(xp.x + v4.x * (xc.x - xp.x)); ov.y  = f2bf(xp.y + v4.y * (xc.y - xp.y));
    ov.z  = f2bf(xp.z + v4.z * (xc.z - xp.z)); ov.w  = f2bf(xp.w + v4.w * (xc.w - xp.w));
    orr.x = f2bf(xp.x + r4.x * (xc.x - xp.x)); orr.y = f2bf(xp.y + r4.y * (xc.y - xp.y));
    orr.z = f2bf(xp.z + r4.z * (xc.z - xp.z)); orr.w = f2bf(xp.w + r4.w * (xc.w - xp.w));
    og.x  = f2bf(xp.x + g4.x * (xc.x - xp.x)); og.y  = f2bf(xp.y + g4.y * (xc.y - xp.y));
    og.z  = f2bf(xp.z + g4.z * (xc.z - xp.z)); og.w  = f2bf(xp.w + g4.w * (xc.w - xp.w));
    *(ushort4*)(xk + f) = ok;
    *(ushort4*)(xv + f) = ov;
    *(ushort4*)(xr + f) = orr;
    *(ushort4*)(xg + f) = og;
}

// ---------------- channel-mix combine (2 outputs, bf16) ----------------
__global__ __launch_bounds__(256) void mix2_kernel(const float* __restrict__ xln,
    const float* __restrict__ mk, const float* __restrict__ mr,
    u16* __restrict__ xk, u16* __restrict__ xr)
{
    int i4 = blockIdx.x * 256 + threadIdx.x;
    int f = i4 << 2;
    int c = f & (CC - 1);
    int t = (f >> 10) & (TT - 1);
    float4 xc = *(const float4*)(xln + f);
    float4 xp = make_float4(0.f, 0.f, 0.f, 0.f);
    if (t) xp = *(const float4*)(xln + f - CC);
    float4 k4 = *(const float4*)(mk + c);
    float4 r4 = *(const float4*)(mr + c);
    ushort4 ok, orr;
    ok.x  = f2bf(xp.x + k4.x * (xc.x - xp.x)); ok.y  = f2bf(xp.y + k4.y * (xc.y - xp.y));
    ok.z  = f2bf(xp.z + k4.z * (xc.z - xp.z)); ok.w  = f2bf(xp.w + k4.w * (xc.w - xp.w));
    orr.x = f2bf(xp.x + r4.x * (xc.x - xp.x)); orr.y = f2bf(xp.y + r4.y * (xc.y - xp.y));
    orr.z = f2bf(xp.z + r4.z * (xc.z - xp.z)); orr.w = f2bf(xp.w + r4.w * (xc.w - xp.w));
    *(ushort4*)(xk + f) = ok;
    *(ushort4*)(xr + f) = orr;
}

// ---------------- fp32 -> bf16 weight conversion (all weights, one kernel) ----------------
struct ConvArgs {
    const float* src[8];
    u16* dst[8];
    int start4[8];   // prefix starts in float4 units
};
__global__ __launch_bounds__(256) void conv_kernel(ConvArgs a, int total4)
{
    int i4 = blockIdx.x * 256 + threadIdx.x;
    if (i4 >= total4) return;
    int s = 0;
#pragma unroll
    for (int j = 1; j < 8; ++j) if (i4 >= a.start4[j]) s = j;
    int l4 = i4 - a.start4[s];
    float4 v = ((const float4*)a.src[s])[l4];
    ushort4 o; o.x = f2bf(v.x); o.y = f2bf(v.y); o.z = f2bf(v.z); o.w = f2bf(v.w);
    ((ushort4*)a.dst[s])[l4] = o;
}

// ---------------- bf16 MFMA GEMM: Y(M,N) = A(M,K) @ Bw(N,K)^T, m97-style ----------------
// EPI: 0 plain f32 | 1 silu f32 | 2 aux1+v f32 | 3 relu(v)^2 -> bf16 | 4 sigmoid f32 | 5 aux1+aux2*v f32
template<int EPI>
__global__ __launch_bounds__(256) void gemm_bt(
    const u16* __restrict__ A, const u16* __restrict__ Bw,
    float* __restrict__ Cf, u16* __restrict__ Cbf,
    const float* __restrict__ aux1, const float* __restrict__ aux2,
    int Mdim, int Ndim, int Kdim)
{
    __shared__ u16 As[128 * 32];
    __shared__ u16 Bs[128 * 32];
    int tid = threadIdx.x;
    int w = tid >> 6, lane = tid & 63;
    int bx = blockIdx.x, by = blockIdx.y;
    int rowBase = by * 128, colBase = bx * 128;
    int wr = w >> 1, wc = w & 1;
    int fr = lane & 15, fk = (lane >> 4) * 8;

    f32x4 acc[4][4] = {};

    int nK = Kdim >> 5;
    for (int kt = 0; kt < nK; ++kt) {
        int k0 = kt << 5;
#pragma unroll
        for (int q = 0; q < 2; ++q) {
            int c = w * 128 + q * 64 + lane;          // chunk id 0..511, 16B each
            const u16* ga = A + (size_t)(rowBase + (c >> 2)) * Kdim + k0 + ((c & 3) << 3);
            __builtin_amdgcn_global_load_lds(
                (const __attribute__((address_space(1))) uint32_t*)(const void*)ga,
                (__attribute__((address_space(3))) uint32_t*)(void*)(As + (size_t)(w * 128 + q * 64) * 8),
                16, 0, 0);
            const u16* gb = Bw + (size_t)(colBase + (c >> 2)) * Kdim + k0 + ((c & 3) << 3);
            __builtin_amdgcn_global_load_lds(
                (const __attribute__((address_space(1))) uint32_t*)(const void*)gb,
                (__attribute__((address_space(3))) uint32_t*)(void*)(Bs + (size_t)(w * 128 + q * 64) * 8),
                16, 0, 0);
        }
        __syncthreads();
        short8 af[4], bf[4];
#pragma unroll
        for (int m = 0; m < 4; ++m)
            af[m] = *(const short8*)&As[(wr * 64 + m * 16 + fr) * 32 + fk];
#pragma unroll
        for (int n = 0; n < 4; ++n)
            bf[n] = *(const short8*)&Bs[(wc * 64 + n * 16 + fr) * 32 + fk];
#pragma unroll
        for (int m = 0; m < 4; ++m)
#pragma unroll
            for (int n = 0; n < 4; ++n)
                acc[m][n] = __builtin_amdgcn_mfma_f32_16x16x32_bf16(af[m], bf[n], acc[m][n], 0, 0, 0);
        __syncthreads();
    }

    int r0 = rowBase + wr * 64, c0 = colBase + wc * 64;
#pragma unroll
    for (int m = 0; m < 4; ++m) {
#pragma unroll
        for (int n = 0; n < 4; ++n) {
#pragma unroll
            for (int rg = 0; rg < 4; ++rg) {
                int gr = r0 + m * 16 + (lane >> 4) * 4 + rg;
                int gc = c0 + n * 16 + (lane & 15);
                size_t idx = (size_t)gr * Ndim + gc;
                float v = acc[m][n][rg];
                if (EPI == 0) Cf[idx] = v;
                else if (EPI == 1) Cf[idx] = v / (1.f + __expf(-v));
                else if (EPI == 2) Cf[idx] = aux1[idx] + v;
                else if (EPI == 3) { float rr = v > 0.f ? v : 0.f; Cbf[idx] = f2bf(rr * rr); }
                else if (EPI == 4) Cf[idx] = 1.f / (1.f + __expf(-v));
                else Cf[idx] = aux1[idx] + aux2[idx] * v;
            }
        }
    }
}

// ================= WKV5 chunk-parallel scan =================
// Layout shared by the 3 phases:
//  - block handles (b, h, jb, [chunk c]): columns j = jb*16 + jj, all 64 rows i.
//  - lane = g*16 + jj; lane's state slice: S[ii] for i = g*16+ii, column j.
//  - state buffers indexed: (((b*HH+h)*PCH + c)*NN + i)*NN + j

__device__ __forceinline__ size_t sidx(int b, int h, int c, int i, int j) {
    return ((((size_t)b * HH + h) * PCH + c) * NN + i) * NN + j;
}

// Phase 1: local decay-weighted state sum per chunk (k,v only).
__global__ __launch_bounds__(64) void wkv_p1(
    const float* __restrict__ k, const float* __restrict__ v,
    const float* __restrict__ decay, float* __restrict__ Sloc)
{
    int blk = blockIdx.x;
    int c  = blk & (PCH - 1);
    int jb = (blk >> 4) & 3;
    int h  = (blk >> 6) & (HH - 1);
    int b  = blk >> 10;
    int lane = threadIdx.x;
    int jj = lane & 15, g = lane >> 4;
    __shared__ float kbufS[64];
    float S[16], ew[16];
#pragma unroll
    for (int ii = 0; ii < 16; ++ii) {
        int i = g * 16 + ii;
        S[ii] = 0.f;
        ew[ii] = expf(-expf(decay[h * NN + i]));
    }
    const size_t base = ((size_t)b * TT + c * LCH) * CC + h * NN;
    const float* kb = k + base;
    const float* vb = v + base + jb * 16;

    for (int t = 0; t < LCH; ++t) {
        size_t off = (size_t)t * CC;
        float kv_ = kb[off + lane];
        float vv  = vb[off + jj];
        kbufS[lane] = kv_;
        __syncthreads();
        float4 kq[4];
#pragma unroll
        for (int q = 0; q < 4; ++q) kq[q] = ((const float4*)kbufS)[g * 4 + q];
        const float* kf = (const float*)kq;
#pragma unroll
        for (int ii = 0; ii < 16; ++ii)
            S[ii] = fmaf(ew[ii], S[ii], kf[ii] * vv);
        __syncthreads();
    }
#pragma unroll
    for (int ii = 0; ii < 16; ++ii)
        Sloc[sidx(b, h, c, g * 16 + ii, jb * 16 + jj)] = S[ii];
}

// Phase 2: serial combine over chunks: Sst[c] = state before chunk c.
__global__ __launch_bounds__(64) void wkv_p2(
    const float* __restrict__ decay,
    const float* __restrict__ Sloc, float* __restrict__ Sst)
{
    int blk = blockIdx.x;           // B*H*4
    int jb = blk & 3;
    int h  = (blk >> 2) & (HH - 1);
    int b  = blk >> 6;
    int lane = threadIdx.x;
    int jj = lane & 15, g = lane >> 4;
    float Srun[16], ewL[16];
#pragma unroll
    for (int ii = 0; ii < 16; ++ii) {
        int i = g * 16 + ii;
        Srun[ii] = 0.f;
        ewL[ii] = expf(-expf(decay[h * NN + i]) * (float)LCH);   // ew^L
    }
    int j = jb * 16 + jj;
    for (int c = 0; c < PCH; ++c) {
#pragma unroll
        for (int ii = 0; ii < 16; ++ii) {
            size_t id = sidx(b, h, c, g * 16 + ii, j);
            Sst[id] = Srun[ii];
            Srun[ii] = fmaf(ewL[ii], Srun[ii], Sloc[id]);
        }
    }
}

// Phase 3: per-chunk output scan starting from Sst.
__global__ __launch_bounds__(64) void wkv_p3(
    const float* __restrict__ r, const float* __restrict__ k, const float* __restrict__ v,
    const float* __restrict__ decay, const float* __restrict__ u,
    const float* __restrict__ Sst, float* __restrict__ y)
{
    int blk = blockIdx.x;
    int c  = blk & (PCH - 1);
    int jb = (blk >> 4) & 3;
    int h  = (blk >> 6) & (HH - 1);
    int b  = blk >> 10;
    int lane = threadIdx.x;
    int jj = lane & 15, g = lane >> 4;
    __shared__ float rkbuf[128];
    float S[16], uu[16], ew[16];
#pragma unroll
    for (int ii = 0; ii < 16; ++ii) {
        int i = g * 16 + ii;
        S[ii] = Sst[sidx(b, h, c, i, jb * 16 + jj)];
        ew[ii] = expf(-expf(decay[h * NN + i]));
        uu[ii] = u[h * NN + i];
    }
    const size_t base = ((size_t)b * TT + c * LCH) * CC + h * NN;
    const float* rb = r + base;
    const float* kb = k + base;
    const float* vb = v + base + jb * 16;
    float* yb = y + base + jb * 16;

    for (int t = 0; t < LCH; ++t) {
        size_t off = (size_t)t * CC;
        float rv  = rb[off + lane];
        float kv_ = kb[off + lane];
        float vv  = vb[off + jj];
        rkbuf[2 * lane]     = rv;
        rkbuf[2 * lane + 1] = kv_;
        __syncthreads();
        float acc = 0.f;
        const float2* rk2 = (const float2*)rkbuf;
#pragma unroll
        for (int ii = 0; ii < 16; ++ii) {
            float2 p = rk2[g * 16 + ii];
            float kvv = p.y * vv;
            float t1 = fmaf(uu[ii], kvv, S[ii]);      // S_old + u*k*v
            acc = fmaf(p.x, t1, acc);
            S[ii] = fmaf(ew[ii], S[ii], kvv);         // S = ew*S + k*v
        }
        acc += __shfl_xor(acc, 16);
        acc += __shfl_xor(acc, 32);
        if (g == 0) yb[off + jj] = acc;
        __syncthreads();
    }
}

// ---------------- GroupNorm(y/8)*w+b, multiply by silu(g), -> bf16 ----------------
__global__ __launch_bounds__(256) void gn_kernel(const float* __restrict__ y,
    const float* __restrict__ gsilu, const float* __restrict__ w, const float* __restrict__ b,
    u16* __restrict__ og)
{
    int row = blockIdx.x;          // b*T + t
    int tid = threadIdx.x;
    int head = tid >> 4, q = tid & 15;
    size_t base = (size_t)row * CC + head * NN + q * 4;
    float4 v = *(const float4*)(y + base);
    v.x *= 0.125f; v.y *= 0.125f; v.z *= 0.125f; v.w *= 0.125f;
    float s  = v.x + v.y + v.z + v.w;
    float ss = v.x*v.x + v.y*v.y + v.z*v.z + v.w*v.w;
#pragma unroll
    for (int m = 1; m < 16; m <<= 1) { s += __shfl_xor(s, m); ss += __shfl_xor(ss, m); }
    float mean = s * (1.f / NN);
    float var  = ss * (1.f / NN) - mean * mean;
    float inv  = rsqrtf(var + EPS_);
    int cb = head * NN + q * 4;
    float4 w4 = *(const float4*)(w + cb);
    float4 b4 = *(const float4*)(b + cb);
    float4 g4 = *(const float4*)(gsilu + base);
    ushort4 o;
    o.x = f2bf(((v.x - mean) * inv * w4.x + b4.x) * g4.x);
    o.y = f2bf(((v.y - mean) * inv * w4.y + b4.y) * g4.y);
    o.z = f2bf(((v.z - mean) * inv * w4.z + b4.z) * g4.z);
    o.w = f2bf(((v.w - mean) * inv * w4.w + b4.w) * g4.w);
    *(ushort4*)(og + base) = o;
}

// ---------------- launcher ----------------
extern "C" void kernel_launch(void* const* d_in, const int* in_sizes, int n_in,
                              void* d_out, int out_size, void* d_ws, size_t ws_size,
                              hipStream_t stream)
{
    const float* x       = (const float*)d_in[0];
    const float* ln1_w   = (const float*)d_in[1];
    const float* ln1_b   = (const float*)d_in[2];
    const float* ln2_w   = (const float*)d_in[3];
    const float* ln2_b   = (const float*)d_in[4];
    const float* tm_mix_k= (const float*)d_in[5];
    const float* tm_mix_v= (const float*)d_in[6];
    const float* tm_mix_r= (const float*)d_in[7];
    const float* tm_mix_g= (const float*)d_in[8];
    const float* tm_decay= (const float*)d_in[9];
    const float* tm_u    = (const float*)d_in[10];
    const float* Wr      = (const float*)d_in[11];
    const float* Wk      = (const float*)d_in[12];
    const float* Wv      = (const float*)d_in[13];
    const float* Wg      = (const float*)d_in[14];
    const float* Wo      = (const float*)d_in[15];
    const float* lnx_w   = (const float*)d_in[16];
    const float* lnx_b   = (const float*)d_in[17];
    const float* cm_mix_k= (const float*)d_in[18];
    const float* cm_mix_r= (const float*)d_in[19];
    const float* cm_Wk   = (const float*)d_in[20];
    const float* cm_Wr   = (const float*)d_in[21];
    const float* cm_Wv   = (const float*)d_in[22];

    char* ws = (char*)d_ws;
    auto MB = [](size_t m) { return m * 1024ull * 1024ull; };
    float* xln    = (float*)(ws + 0);         // 16MB (reused for ln2)
    u16*   xk     = (u16*)(ws + MB(16));      // 8MB (reused for cm xk)
    u16*   xv     = (u16*)(ws + MB(24));      // 8MB
    u16*   xr     = (u16*)(ws + MB(32));      // 8MB (reused for cm xr)
    u16*   xg     = (u16*)(ws + MB(40));      // 8MB
    float* rbuf   = (float*)(ws + MB(48));    // 16MB
    float* kbuf_f = (float*)(ws + MB(64));    // 16MB
    float* vbuf   = (float*)(ws + MB(80));    // 16MB
    float* gbuf   = (float*)(ws + MB(96));    // 16MB (silu g; reused for sr)
    float* ybuf   = (float*)(ws + MB(112));   // 16MB
    u16*   og     = (u16*)(ws + MB(128));     // 8MB
    float* x1     = (float*)(ws + MB(136));   // 16MB
    u16*   kbuf2  = (u16*)(ws + MB(48));      // 32MB bf16 (B,T,FFN), overlaps r/k (dead by then)
    // WKV chunk-state buffers (16.78 MB each), in regions dead during the scan:
    float* Sloc   = (float*)(ws + MB(16));    // overlaps xk/xv/xr (dead after projections)
    float* Sst    = (float*)(ws + MB(128));   // overlaps og/x1 (written only after WKV)
    u16*   wbf    = (u16*)(ws + MB(152));     // bf16 weights, 30MB total
    u16* Wr_b   = wbf;
    u16* Wk_b   = wbf + (1u << 20) * 1;
    u16* Wv_b   = wbf + (1u << 20) * 2;
    u16* Wg_b   = wbf + (1u << 20) * 3;
    u16* Wo_b   = wbf + (1u << 20) * 4;
    u16* cmWk_b = wbf + (1u << 20) * 5;       // 4M elems
    u16* cmWr_b = cmWk_b + (4u << 20);
    u16* cmWv_b = cmWr_b + (1u << 20);        // 4M elems

    // 1. weights fp32 -> bf16
    ConvArgs ca;
    ca.src[0] = Wr;    ca.dst[0] = Wr_b;
    ca.src[1] = Wk;    ca.dst[1] = Wk_b;
    ca.src[2] = Wv;    ca.dst[2] = Wv_b;
    ca.src[3] = Wg;    ca.dst[3] = Wg_b;
    ca.src[4] = Wo;    ca.dst[4] = Wo_b;
    ca.src[5] = cm_Wk; ca.dst[5] = cmWk_b;
    ca.src[6] = cm_Wr; ca.dst[6] = cmWr_b;
    ca.src[7] = cm_Wv; ca.dst[7] = cmWv_b;
    int q = (CC * CC) / 4;   // 262144
    int st[8] = {0, q, 2*q, 3*q, 4*q, 5*q, 5*q + 4*q, 5*q + 4*q + q};
    for (int i = 0; i < 8; ++i) ca.start4[i] = st[i];
    int total4 = 5*q + 4*q + q + 4*q;  // 14*q = 3,670,016
    conv_kernel<<<(total4 + 255) / 256, 256, 0, stream>>>(ca, total4);

    // 2. LN1 + time-mix
    ln_kernel<<<MM, 256, 0, stream>>>(x, ln1_w, ln1_b, xln);
    mix1_kernel<<<(MM * CC / 4) / 256, 256, 0, stream>>>(xln, tm_mix_k, tm_mix_v, tm_mix_r, tm_mix_g,
                                                         xk, xv, xr, xg);
    // 3. r,k,v,g projections
    dim3 g1(CC / 128, MM / 128);
    gemm_bt<0><<<g1, 256, 0, stream>>>(xr, Wr_b, rbuf,   nullptr, nullptr, nullptr, MM, CC, CC);
    gemm_bt<0><<<g1, 256, 0, stream>>>(xk, Wk_b, kbuf_f, nullptr, nullptr, nullptr, MM, CC, CC);
    gemm_bt<0><<<g1, 256, 0, stream>>>(xv, Wv_b, vbuf,   nullptr, nullptr, nullptr, MM, CC, CC);
    gemm_bt<1><<<g1, 256, 0, stream>>>(xg, Wg_b, gbuf,   nullptr, nullptr, nullptr, MM, CC, CC);

    // 4. WKV5 recurrence — chunk-parallel 3-phase scan
    wkv_p1<<<BB * HH * 4 * PCH, 64, 0, stream>>>(kbuf_f, vbuf, tm_decay, Sloc);
    wkv_p2<<<BB * HH * 4, 64, 0, stream>>>(tm_decay, Sloc, Sst);
    wkv_p3<<<BB * HH * 4 * PCH, 64, 0, stream>>>(rbuf, kbuf_f, vbuf, tm_decay, tm_u, Sst, ybuf);

    // 5. GroupNorm(y/8) * g -> bf16
    gn_kernel<<<MM, 256, 0, stream>>>(ybuf, gbuf, lnx_w, lnx_b, og);

    // 6. x1 = x + og @ Wo^T
    gemm_bt<2><<<g1, 256, 0, stream>>>(og, Wo_b, x1, nullptr, x, nullptr, MM, CC, CC);

    // 7. LN2 + channel-mix
    ln_kernel<<<MM, 256, 0, stream>>>(x1, ln2_w, ln2_b, xln);
    mix2_kernel<<<(MM * CC / 4) / 256, 256, 0, stream>>>(xln, cm_mix_k, cm_mix_r, xk, xr);

    // 8. kbuf = relu(xk @ cm_Wk^T)^2 (bf16); sr = sigmoid(xr @ cm_Wr^T)
    dim3 g6(FFN_ / 128, MM / 128);
    gemm_bt<3><<<g6, 256, 0, stream>>>(xk, cmWk_b, nullptr, kbuf2, nullptr, nullptr, MM, FFN_, CC);
    gemm_bt<4><<<g1, 256, 0, stream>>>(xr, cmWr_b, gbuf, nullptr, nullptr, nullptr, MM, CC, CC);

    // 9. out = x1 + sr * (kbuf @ cm_Wv^T)
    gemm_bt<5><<<g1, 256, 0, stream>>>(kbuf2, cmWv_b, (float*)d_out, nullptr, x1, gbuf, MM, CC, FFN_);
}

// Round 3
// 483.939 us; speedup vs baseline: 2.1409x; 1.2072x over previous
//
#include <hip/hip_runtime.h>
#include <stdint.h>

typedef unsigned short u16;
typedef __attribute__((ext_vector_type(8))) short short8;
typedef __attribute__((ext_vector_type(4))) float f32x4;

#define BB 4
#define TT 1024
#define CC 1024
#define HH 16
#define NN 64
#define MM (BB*TT)        // 4096 rows
#define FFN_ 4096
#define PCH 16            // WKV chunks
#define LCH (TT/PCH)      // 64 steps per chunk
static constexpr float EPS_ = 1e-5f;

__device__ __forceinline__ u16 f2bf(float f) {
    union { float f; uint32_t u; } x; x.f = f;
    uint32_t r = x.u + 0x7fff + ((x.u >> 16) & 1);   // RNE
    return (u16)(r >> 16);
}
__device__ __forceinline__ float bf2f(u16 b) {
    union { uint32_t u; float f; } x; x.u = ((uint32_t)b) << 16; return x.f;
}

#define VMW8() asm volatile("s_waitcnt vmcnt(8)" ::: "memory")
#define VMW4() asm volatile("s_waitcnt vmcnt(4)" ::: "memory")
#define VMW0() asm volatile("s_waitcnt vmcnt(0)" ::: "memory")
#define BARRIER() do { asm volatile("" ::: "memory"); __builtin_amdgcn_s_barrier(); asm volatile("" ::: "memory"); } while (0)

// ---------------- LayerNorm -> concat-bf16 z: z[row][0:1024]=ln, z[row+1][1024:2048]=ln ----------------
__global__ __launch_bounds__(256) void lnz_kernel(const float* __restrict__ x,
    const float* __restrict__ w, const float* __restrict__ b, u16* __restrict__ z)
{
    int row = blockIdx.x;
    int tid = threadIdx.x;
    const float* xr = x + (size_t)row * CC;
    float4 v = ((const float4*)xr)[tid];
    float s  = v.x + v.y + v.z + v.w;
    float ss = v.x*v.x + v.y*v.y + v.z*v.z + v.w*v.w;
#pragma unroll
    for (int m = 1; m < 64; m <<= 1) { s += __shfl_xor(s, m); ss += __shfl_xor(ss, m); }
    __shared__ float as_[4], bs_[4];
    int wv = tid >> 6, ln = tid & 63;
    if (ln == 0) { as_[wv] = s; bs_[wv] = ss; }
    __syncthreads();
    s  = as_[0] + as_[1] + as_[2] + as_[3];
    ss = bs_[0] + bs_[1] + bs_[2] + bs_[3];
    float mean = s * (1.f / CC);
    float var  = ss * (1.f / CC) - mean * mean;
    float inv  = rsqrtf(var + EPS_);
    float4 w4 = ((const float4*)w)[tid];
    float4 b4 = ((const float4*)b)[tid];
    ushort4 o;
    o.x = f2bf((v.x - mean) * inv * w4.x + b4.x);
    o.y = f2bf((v.y - mean) * inv * w4.y + b4.y);
    o.z = f2bf((v.z - mean) * inv * w4.z + b4.z);
    o.w = f2bf((v.w - mean) * inv * w4.w + b4.w);
    int t = row & (TT - 1);
    *(ushort4*)(z + (size_t)row * 2048 + tid * 4) = o;
    if (t < TT - 1) *(ushort4*)(z + (size_t)(row + 1) * 2048 + 1024 + tid * 4) = o;
    if (t == 0) {
        ushort4 zz; zz.x = 0; zz.y = 0; zz.z = 0; zz.w = 0;
        *(ushort4*)(z + (size_t)row * 2048 + 1024 + tid * 4) = zz;
    }
}

// ---------------- channel-mix combine from z2 (2 outputs, bf16) ----------------
__global__ __launch_bounds__(256) void mix2b_kernel(const u16* __restrict__ z2,
    const float* __restrict__ mk, const float* __restrict__ mr,
    u16* __restrict__ xk, u16* __restrict__ xr)
{
    int idx = blockIdx.x * 256 + threadIdx.x;   // 1M threads, 4 elems each
    int row = idx >> 8, c = (idx & 255) << 2;
    const u16* zr = z2 + (size_t)row * 2048;
    ushort4 zc = *(const ushort4*)(zr + c);
    ushort4 zp = *(const ushort4*)(zr + 1024 + c);
    float xc0 = bf2f(zc.x), xc1 = bf2f(zc.y), xc2 = bf2f(zc.z), xc3 = bf2f(zc.w);
    float xp0 = bf2f(zp.x), xp1 = bf2f(zp.y), xp2 = bf2f(zp.z), xp3 = bf2f(zp.w);
    float4 k4 = *(const float4*)(mk + c);
    float4 r4 = *(const float4*)(mr + c);
    ushort4 ok, orr;
    ok.x  = f2bf(xp0 + k4.x * (xc0 - xp0)); ok.y  = f2bf(xp1 + k4.y * (xc1 - xp1));
    ok.z  = f2bf(xp2 + k4.z * (xc2 - xp2)); ok.w  = f2bf(xp3 + k4.w * (xc3 - xp3));
    orr.x = f2bf(xp0 + r4.x * (xc0 - xp0)); orr.y = f2bf(xp1 + r4.y * (xc1 - xp1));
    orr.z = f2bf(xp2 + r4.z * (xc2 - xp2)); orr.w = f2bf(xp3 + r4.w * (xc3 - xp3));
    size_t f = (size_t)row * 1024 + c;
    *(ushort4*)(xk + f) = ok;
    *(ushort4*)(xr + f) = orr;
}

// ---------------- merged projection weight build: W4'(4096,2048) bf16 ----------------
__global__ __launch_bounds__(256) void convW4_kernel(
    const float* __restrict__ Wr, const float* __restrict__ Wk,
    const float* __restrict__ Wv, const float* __restrict__ Wg,
    const float* __restrict__ mr, const float* __restrict__ mk,
    const float* __restrict__ mv, const float* __restrict__ mg,
    u16* __restrict__ W4p)
{
    int idx = blockIdx.x * 256 + threadIdx.x;   // n*256 + c4, 1M total
    int n = idx >> 8, c = (idx & 255) << 2;
    int sel = n >> 10, nr = n & 1023;
    const float* W = sel == 0 ? Wr : sel == 1 ? Wk : sel == 2 ? Wv : Wg;
    const float* mx = sel == 0 ? mr : sel == 1 ? mk : sel == 2 ? mv : mg;
    float4 w4 = *(const float4*)(W + (size_t)nr * 1024 + c);
    float4 m4 = *(const float4*)(mx + c);
    ushort4 a, bq;
    a.x  = f2bf(w4.x * m4.x); a.y  = f2bf(w4.y * m4.y);
    a.z  = f2bf(w4.z * m4.z); a.w  = f2bf(w4.w * m4.w);
    bq.x = f2bf(w4.x * (1.f - m4.x)); bq.y = f2bf(w4.y * (1.f - m4.y));
    bq.z = f2bf(w4.z * (1.f - m4.z)); bq.w = f2bf(w4.w * (1.f - m4.w));
    *(ushort4*)(W4p + (size_t)n * 2048 + c) = a;
    *(ushort4*)(W4p + (size_t)n * 2048 + 1024 + c) = bq;
}

// ---------------- fp32 -> bf16 weight conversion (segments) ----------------
struct ConvArgs {
    const float* src[8];
    u16* dst[8];
    int start4[8];
};
__global__ __launch_bounds__(256) void conv_kernel(ConvArgs a, int total4)
{
    int i4 = blockIdx.x * 256 + threadIdx.x;
    if (i4 >= total4) return;
    int s = 0;
#pragma unroll
    for (int j = 1; j < 8; ++j) if (i4 >= a.start4[j]) s = j;
    int l4 = i4 - a.start4[s];
    float4 v = ((const float4*)a.src[s])[l4];
    ushort4 o; o.x = f2bf(v.x); o.y = f2bf(v.y); o.z = f2bf(v.z); o.w = f2bf(v.w);
    ((ushort4*)a.dst[s])[l4] = o;
}

// ================ 256x256-tile 8-phase bf16 GEMM (T1+T3+T4+T5) ================
// C(M,N) = A(M,K_window) @ Bw(N,K_window)^T ; BK=32, ring-4 LDS, 512 threads.
// EPI: 0 plain f32 | 3 relu(v)^2 -> bf16 | 6 rkvg (silu for cols>=3072) | 7 split-K partial f32
__device__ __forceinline__ void stage_tile(const u16* gbase, int rbase, int ldk,
                                           int kcol, u16* ldsbase, int tid)
{
#pragma unroll
    for (int rd = 0; rd < 2; ++rd) {
        int row = rd * 128 + (tid >> 2);
        const u16* src = gbase + (size_t)(rbase + row) * ldk + kcol + ((tid & 3) << 3);
        u16* dst = ldsbase + row * 32 + ((tid & 3) << 3);
        __builtin_amdgcn_global_load_lds(
            (const __attribute__((address_space(1))) uint32_t*)(const void*)src,
            (__attribute__((address_space(3))) uint32_t*)(void*)dst, 16, 0, 0);
    }
}

template<int EPI>
__global__ __launch_bounds__(512, 2) void gemm8(
    const u16* __restrict__ A, const u16* __restrict__ Bw,
    float* __restrict__ Cf, u16* __restrict__ Cbf,
    int Mdim, int Ndim, int Kdim, int kLen)
{
    __shared__ u16 As[4 * 8192];
    __shared__ u16 Bs[4 * 8192];
    int tid = threadIdx.x;
    int wid = tid >> 6, lane = tid & 63;
    int wm = wid >> 2, wn = wid & 3;
    int f = lane & 15, g = lane >> 4;

    // T1 bijective XCD swizzle over flattened (x,y)
    int nwg = gridDim.x * gridDim.y;
    int bid = blockIdx.y * gridDim.x + blockIdx.x;
    int qq = nwg >> 3, r8 = nwg & 7;
    int xcd = bid & 7, lid = bid >> 3;
    int swz = (xcd < r8 ? xcd * (qq + 1) : r8 * (qq + 1) + (xcd - r8) * qq) + lid;
    int bx = swz % gridDim.x, by = swz / gridDim.x;
    int rowBase = by * 256, colBase = bx * 256;
    int kOff = blockIdx.z * kLen;
    int NT = kLen >> 5;
    if (EPI == 7) Cf += (size_t)blockIdx.z * Mdim * Ndim;

    f32x4 acc[8][4] = {};

    // prologue: stage ktiles 0,1,2 (A then B each)
    stage_tile(A,  rowBase, Kdim, kOff,      As, tid);
    stage_tile(Bw, colBase, Kdim, kOff,      Bs, tid);
    if (NT > 1) {
        stage_tile(A,  rowBase, Kdim, kOff + 32, As + 8192, tid);
        stage_tile(Bw, colBase, Kdim, kOff + 32, Bs + 8192, tid);
    }
    if (NT > 2) {
        stage_tile(A,  rowBase, Kdim, kOff + 64, As + 2 * 8192, tid);
        stage_tile(Bw, colBase, Kdim, kOff + 64, Bs + 2 * 8192, tid);
    }

    for (int t = 0; t < NT; ++t) {
        if (t < NT - 2) { VMW8(); } else if (t == NT - 2) { VMW4(); } else { VMW0(); }
        BARRIER();
        const u16* Asl = As + (t & 3) * 8192;
        const u16* Bsl = Bs + (t & 3) * 8192;
        short8 bfr[4], afr[4];
#pragma unroll
        for (int n = 0; n < 4; ++n)
            bfr[n] = *(const short8*)(Bsl + (wn * 64 + n * 16 + f) * 32 + g * 8);
#pragma unroll
        for (int m = 0; m < 4; ++m)
            afr[m] = *(const short8*)(Asl + (wm * 128 + m * 16 + f) * 32 + g * 8);
        if (t + 3 < NT)
            stage_tile(A, rowBase, Kdim, kOff + (t + 3) * 32, As + ((t + 3) & 3) * 8192, tid);
        __builtin_amdgcn_s_setprio(1);
#pragma unroll
        for (int m = 0; m < 4; ++m)
#pragma unroll
            for (int n = 0; n < 4; ++n)
                acc[m][n] = __builtin_amdgcn_mfma_f32_16x16x32_bf16(afr[m], bfr[n], acc[m][n], 0, 0, 0);
        __builtin_amdgcn_s_setprio(0);
        // phase 2: upper 64 rows of the wave tile
#pragma unroll
        for (int m = 0; m < 4; ++m)
            afr[m] = *(const short8*)(Asl + (wm * 128 + 64 + m * 16 + f) * 32 + g * 8);
        if (t + 3 < NT)
            stage_tile(Bw, colBase, Kdim, kOff + (t + 3) * 32, Bs + ((t + 3) & 3) * 8192, tid);
        __builtin_amdgcn_s_setprio(1);
#pragma unroll
        for (int m = 0; m < 4; ++m)
#pragma unroll
            for (int n = 0; n < 4; ++n)
                acc[4 + m][n] = __builtin_amdgcn_mfma_f32_16x16x32_bf16(afr[m], bfr[n], acc[4 + m][n], 0, 0, 0);
        __builtin_amdgcn_s_setprio(0);
    }

    int r0 = rowBase + wm * 128, c0 = colBase + wn * 64;
    bool dsilu = (EPI == 6) && (colBase >= 3072);
#pragma unroll
    for (int am = 0; am < 8; ++am) {
#pragma unroll
        for (int n = 0; n < 4; ++n) {
#pragma unroll
            for (int rg = 0; rg < 4; ++rg) {
                int gr = r0 + am * 16 + (lane >> 4) * 4 + rg;
                int gc = c0 + n * 16 + (lane & 15);
                size_t idx = (size_t)gr * Ndim + gc;
                float v = acc[am][n][rg];
                if (EPI == 3) { float rr = v > 0.f ? v : 0.f; Cbf[idx] = f2bf(rr * rr); }
                else if (EPI == 6) Cf[idx] = dsilu ? v / (1.f + __expf(-v)) : v;
                else Cf[idx] = v;
            }
        }
    }
}

// ---------------- legacy 128x128 MFMA GEMM (verified) for N=1024 shapes ----------------
// EPI: 2 aux1+v f32 | 4 sigmoid f32
template<int EPI>
__global__ __launch_bounds__(256) void gemm_bt(
    const u16* __restrict__ A, const u16* __restrict__ Bw,
    float* __restrict__ Cf, u16* __restrict__ Cbf,
    const float* __restrict__ aux1, const float* __restrict__ aux2,
    int Mdim, int Ndim, int Kdim)
{
    __shared__ u16 As[128 * 32];
    __shared__ u16 Bs[128 * 32];
    int tid = threadIdx.x;
    int w = tid >> 6, lane = tid & 63;
    int bx = blockIdx.x, by = blockIdx.y;
    int rowBase = by * 128, colBase = bx * 128;
    int wr = w >> 1, wc = w & 1;
    int fr = lane & 15, fk = (lane >> 4) * 8;

    f32x4 acc[4][4] = {};

    int nK = Kdim >> 5;
    for (int kt = 0; kt < nK; ++kt) {
        int k0 = kt << 5;
#pragma unroll
        for (int q = 0; q < 2; ++q) {
            int c = w * 128 + q * 64 + lane;
            const u16* ga = A + (size_t)(rowBase + (c >> 2)) * Kdim + k0 + ((c & 3) << 3);
            __builtin_amdgcn_global_load_lds(
                (const __attribute__((address_space(1))) uint32_t*)(const void*)ga,
                (__attribute__((address_space(3))) uint32_t*)(void*)(As + (size_t)(w * 128 + q * 64) * 8),
                16, 0, 0);
            const u16* gb = Bw + (size_t)(colBase + (c >> 2)) * Kdim + k0 + ((c & 3) << 3);
            __builtin_amdgcn_global_load_lds(
                (const __attribute__((address_space(1))) uint32_t*)(const void*)gb,
                (__attribute__((address_space(3))) uint32_t*)(void*)(Bs + (size_t)(w * 128 + q * 64) * 8),
                16, 0, 0);
        }
        __syncthreads();
        short8 af[4], bf[4];
#pragma unroll
        for (int m = 0; m < 4; ++m)
            af[m] = *(const short8*)&As[(wr * 64 + m * 16 + fr) * 32 + fk];
#pragma unroll
        for (int n = 0; n < 4; ++n)
            bf[n] = *(const short8*)&Bs[(wc * 64 + n * 16 + fr) * 32 + fk];
#pragma unroll
        for (int m = 0; m < 4; ++m)
#pragma unroll
            for (int n = 0; n < 4; ++n)
                acc[m][n] = __builtin_amdgcn_mfma_f32_16x16x32_bf16(af[m], bf[n], acc[m][n], 0, 0, 0);
        __syncthreads();
    }

    int r0 = rowBase + wr * 64, c0 = colBase + wc * 64;
#pragma unroll
    for (int m = 0; m < 4; ++m) {
#pragma unroll
        for (int n = 0; n < 4; ++n) {
#pragma unroll
            for (int rg = 0; rg < 4; ++rg) {
                int gr = r0 + m * 16 + (lane >> 4) * 4 + rg;
                int gc = c0 + n * 16 + (lane & 15);
                size_t idx = (size_t)gr * Ndim + gc;
                float v = acc[m][n][rg];
                if (EPI == 2) Cf[idx] = aux1[idx] + v;
                else if (EPI == 4) Cf[idx] = 1.f / (1.f + __expf(-v));
                else Cf[idx] = v;
            }
        }
    }
}

// ================= WKV5 chunk-parallel scan (strided inputs from rkvg) =================
__device__ __forceinline__ size_t sidx(int b, int h, int c, int i, int j) {
    return ((((size_t)b * HH + h) * PCH + c) * NN + i) * NN + j;
}

__global__ __launch_bounds__(64) void wkv_p1(
    const float* __restrict__ k, const float* __restrict__ v,
    const float* __restrict__ decay, float* __restrict__ Sloc, int ld)
{
    int blk = blockIdx.x;
    int c  = blk & (PCH - 1);
    int jb = (blk >> 4) & 3;
    int h  = (blk >> 6) & (HH - 1);
    int b  = blk >> 10;
    int lane = threadIdx.x;
    int jj = lane & 15, g = lane >> 4;
    __shared__ float kbufS[64];
    float S[16], ew[16];
#pragma unroll
    for (int ii = 0; ii < 16; ++ii) {
        int i = g * 16 + ii;
        S[ii] = 0.f;
        ew[ii] = expf(-expf(decay[h * NN + i]));
    }
    const size_t base = ((size_t)b * TT + c * LCH) * ld + h * NN;
    const float* kb = k + base;
    const float* vb = v + base + jb * 16;

    for (int t = 0; t < LCH; ++t) {
        size_t off = (size_t)t * ld;
        float kv_ = kb[off + lane];
        float vv  = vb[off + jj];
        kbufS[lane] = kv_;
        __syncthreads();
        float4 kq[4];
#pragma unroll
        for (int q = 0; q < 4; ++q) kq[q] = ((const float4*)kbufS)[g * 4 + q];
        const float* kf = (const float*)kq;
#pragma unroll
        for (int ii = 0; ii < 16; ++ii)
            S[ii] = fmaf(ew[ii], S[ii], kf[ii] * vv);
        __syncthreads();
    }
#pragma unroll
    for (int ii = 0; ii < 16; ++ii)
        Sloc[sidx(b, h, c, g * 16 + ii, jb * 16 + jj)] = S[ii];
}

__global__ __launch_bounds__(64) void wkv_p2(
    const float* __restrict__ decay,
    const float* __restrict__ Sloc, float* __restrict__ Sst)
{
    int blk = blockIdx.x;           // B*H*4
    int jb = blk & 3;
    int h  = (blk >> 2) & (HH - 1);
    int b  = blk >> 6;
    int lane = threadIdx.x;
    int jj = lane & 15, g = lane >> 4;
    float Srun[16], ewL[16];
#pragma unroll
    for (int ii = 0; ii < 16; ++ii) {
        int i = g * 16 + ii;
        Srun[ii] = 0.f;
        ewL[ii] = expf(-expf(decay[h * NN + i]) * (float)LCH);
    }
    int j = jb * 16 + jj;
    for (int c = 0; c < PCH; ++c) {
#pragma unroll
        for (int ii = 0; ii < 16; ++ii) {
            size_t id = sidx(b, h, c, g * 16 + ii, j);
            Sst[id] = Srun[ii];
            Srun[ii] = fmaf(ewL[ii], Srun[ii], Sloc[id]);
        }
    }
}

__global__ __launch_bounds__(64) void wkv_p3(
    const float* __restrict__ r, const float* __restrict__ k, const float* __restrict__ v,
    const float* __restrict__ decay, const float* __restrict__ u,
    const float* __restrict__ Sst, float* __restrict__ y, int ld)
{
    int blk = blockIdx.x;
    int c  = blk & (PCH - 1);
    int jb = (blk >> 4) & 3;
    int h  = (blk >> 6) & (HH - 1);
    int b  = blk >> 10;
    int lane = threadIdx.x;
    int jj = lane & 15, g = lane >> 4;
    __shared__ float rkbuf[128];
    float S[16], uu[16], ew[16];
#pragma unroll
    for (int ii = 0; ii < 16; ++ii) {
        int i = g * 16 + ii;
        S[ii] = Sst[sidx(b, h, c, i, jb * 16 + jj)];
        ew[ii] = expf(-expf(decay[h * NN + i]));
        uu[ii] = u[h * NN + i];
    }
    const size_t base = ((size_t)b * TT + c * LCH) * ld + h * NN;
    const float* rb = r + base;
    const float* kb = k + base;
    const float* vb = v + base + jb * 16;
    float* yb = y + (((size_t)b * TT + c * LCH)) * CC + h * NN + jb * 16;

    for (int t = 0; t < LCH; ++t) {
        size_t off = (size_t)t * ld;
        float rv  = rb[off + lane];
        float kv_ = kb[off + lane];
        float vv  = vb[off + jj];
        rkbuf[2 * lane]     = rv;
        rkbuf[2 * lane + 1] = kv_;
        __syncthreads();
        float acc = 0.f;
        const float2* rk2 = (const float2*)rkbuf;
#pragma unroll
        for (int ii = 0; ii < 16; ++ii) {
            float2 p = rk2[g * 16 + ii];
            float kvv = p.y * vv;
            float t1 = fmaf(uu[ii], kvv, S[ii]);
            acc = fmaf(p.x, t1, acc);
            S[ii] = fmaf(ew[ii], S[ii], kvv);
        }
        acc += __shfl_xor(acc, 16);
        acc += __shfl_xor(acc, 32);
        if (g == 0) yb[(size_t)t * CC + jj] = acc;
        __syncthreads();
    }
}

// ---------------- GroupNorm(y/8)*w+b, multiply by silu(g) [pre-applied], -> bf16 ----------------
__global__ __launch_bounds__(256) void gn_kernel(const float* __restrict__ y,
    const float* __restrict__ gsil, const float* __restrict__ w, const float* __restrict__ b,
    u16* __restrict__ og)
{
    int row = blockIdx.x;
    int tid = threadIdx.x;
    int head = tid >> 4, q = tid & 15;
    int cb = head * NN + q * 4;
    size_t base = (size_t)row * CC + cb;
    float4 v = *(const float4*)(y + base);
    v.x *= 0.125f; v.y *= 0.125f; v.z *= 0.125f; v.w *= 0.125f;
    float s  = v.x + v.y + v.z + v.w;
    float ss = v.x*v.x + v.y*v.y + v.z*v.z + v.w*v.w;
#pragma unroll
    for (int m = 1; m < 16; m <<= 1) { s += __shfl_xor(s, m); ss += __shfl_xor(ss, m); }
    float mean = s * (1.f / NN);
    float var  = ss * (1.f / NN) - mean * mean;
    float inv  = rsqrtf(var + EPS_);
    float4 w4 = *(const float4*)(w + cb);
    float4 b4 = *(const float4*)(b + cb);
    float4 g4 = *(const float4*)(gsil + (size_t)row * 4096 + cb);  // silu already applied
    ushort4 o;
    o.x = f2bf(((v.x - mean) * inv * w4.x + b4.x) * g4.x);
    o.y = f2bf(((v.y - mean) * inv * w4.y + b4.y) * g4.y);
    o.z = f2bf(((v.z - mean) * inv * w4.z + b4.z) * g4.z);
    o.w = f2bf(((v.w - mean) * inv * w4.w + b4.w) * g4.w);
    *(ushort4*)(og + base) = o;
}

// ---------------- split-K reduce + sigmoid-gate epilogue ----------------
__global__ __launch_bounds__(256) void reduce_cmv(const float* __restrict__ p,
    const float* __restrict__ x1, const float* __restrict__ sr, float* __restrict__ out)
{
    size_t i = ((size_t)blockIdx.x * 256 + threadIdx.x) * 4;
    const size_t stride = (size_t)MM * 1024;
    float4 a0 = *(const float4*)(p + i);
    float4 a1 = *(const float4*)(p + stride + i);
    float4 a2 = *(const float4*)(p + 2 * stride + i);
    float4 a3 = *(const float4*)(p + 3 * stride + i);
    float4 xv = *(const float4*)(x1 + i);
    float4 sv = *(const float4*)(sr + i);
    float4 o;
    o.x = xv.x + sv.x * (a0.x + a1.x + a2.x + a3.x);
    o.y = xv.y + sv.y * (a0.y + a1.y + a2.y + a3.y);
    o.z = xv.z + sv.z * (a0.z + a1.z + a2.z + a3.z);
    o.w = xv.w + sv.w * (a0.w + a1.w + a2.w + a3.w);
    *(float4*)(out + i) = o;
}

// ---------------- launcher ----------------
extern "C" void kernel_launch(void* const* d_in, const int* in_sizes, int n_in,
                              void* d_out, int out_size, void* d_ws, size_t ws_size,
                              hipStream_t stream)
{
    const float* x       = (const float*)d_in[0];
    const float* ln1_w   = (const float*)d_in[1];
    const float* ln1_b   = (const float*)d_in[2];
    const float* ln2_w   = (const float*)d_in[3];
    const float* ln2_b   = (const float*)d_in[4];
    const float* tm_mix_k= (const float*)d_in[5];
    const float* tm_mix_v= (const float*)d_in[6];
    const float* tm_mix_r= (const float*)d_in[7];
    const float* tm_mix_g= (const float*)d_in[8];
    const float* tm_decay= (const float*)d_in[9];
    const float* tm_u    = (const float*)d_in[10];
    const float* Wr      = (const float*)d_in[11];
    const float* Wk      = (const float*)d_in[12];
    const float* Wv      = (const float*)d_in[13];
    const float* Wg      = (const float*)d_in[14];
    const float* Wo      = (const float*)d_in[15];
    const float* lnx_w   = (const float*)d_in[16];
    const float* lnx_b   = (const float*)d_in[17];
    const float* cm_mix_k= (const float*)d_in[18];
    const float* cm_mix_r= (const float*)d_in[19];
    const float* cm_Wk   = (const float*)d_in[20];
    const float* cm_Wr   = (const float*)d_in[21];
    const float* cm_Wv   = (const float*)d_in[22];

    char* ws = (char*)d_ws;
    auto MB = [](size_t m) { return m * 1024ull * 1024ull; };
    // layout (MiB): [0,16) z1/z2 | [16,80) rkvg -> partials | [80,96) ybuf -> sr
    // [96,104) og -> xk | [104,112) xr | [112,128) Sloc -> x1 | [128,144) W4p -> Sst, [128,160) kbuf2
    // [160,180) small bf16 weights
    u16*   z      = (u16*)(ws + 0);
    float* rkvg   = (float*)(ws + MB(16));
    float* partials = (float*)(ws + MB(16));
    float* ybuf   = (float*)(ws + MB(80));
    float* sr     = (float*)(ws + MB(80));
    u16*   og     = (u16*)(ws + MB(96));
    u16*   xk     = (u16*)(ws + MB(96));
    u16*   xr     = (u16*)(ws + MB(104));
    float* Sloc   = (float*)(ws + MB(112));
    float* x1     = (float*)(ws + MB(112));
    u16*   W4p    = (u16*)(ws + MB(128));
    float* Sst    = (float*)(ws + MB(128));
    u16*   kbuf2  = (u16*)(ws + MB(128));
    u16*   Wo_b   = (u16*)(ws + MB(160));
    u16*   cmWk_b = (u16*)(ws + MB(162));
    u16*   cmWr_b = (u16*)(ws + MB(170));
    u16*   cmWv_b = (u16*)(ws + MB(172));

    // 1. weight prep
    convW4_kernel<<<4096, 256, 0, stream>>>(Wr, Wk, Wv, Wg,
        tm_mix_r, tm_mix_k, tm_mix_v, tm_mix_g, W4p);
    ConvArgs ca;
    ca.src[0] = Wo;    ca.dst[0] = Wo_b;
    ca.src[1] = cm_Wk; ca.dst[1] = cmWk_b;
    ca.src[2] = cm_Wr; ca.dst[2] = cmWr_b;
    ca.src[3] = cm_Wv; ca.dst[3] = cmWv_b;
    int q = (CC * CC) / 4;   // 262144
    ca.start4[0] = 0; ca.start4[1] = q; ca.start4[2] = 5 * q; ca.start4[3] = 6 * q;
    for (int i = 4; i < 8; ++i) { ca.src[i] = Wo; ca.dst[i] = Wo_b; ca.start4[i] = 0x7FFFFFFF; }
    int total4 = 10 * q;
    conv_kernel<<<(total4 + 255) / 256, 256, 0, stream>>>(ca, total4);

    // 2. LN1 -> z1 (concat bf16)
    lnz_kernel<<<MM, 256, 0, stream>>>(x, ln1_w, ln1_b, z);

    // 3. merged r|k|v|g projection: rkvg = z1 @ W4p^T (silu on g cols)
    gemm8<6><<<dim3(16, 16, 1), 512, 0, stream>>>(z, W4p, rkvg, nullptr, MM, 4096, 2048, 2048);

    // 4. WKV5 chunk-parallel scan (strided over rkvg)
    wkv_p1<<<BB * HH * 4 * PCH, 64, 0, stream>>>(rkvg + 1024, rkvg + 2048, tm_decay, Sloc, 4096);
    wkv_p2<<<BB * HH * 4, 64, 0, stream>>>(tm_decay, Sloc, Sst);
    wkv_p3<<<BB * HH * 4 * PCH, 64, 0, stream>>>(rkvg, rkvg + 1024, rkvg + 2048,
                                                 tm_decay, tm_u, Sst, ybuf, 4096);

    // 5. GroupNorm(y/8) * silu(g) -> og bf16
    gn_kernel<<<MM, 256, 0, stream>>>(ybuf, rkvg + 3072, lnx_w, lnx_b, og);

    // 6. x1 = x + og @ Wo^T
    dim3 g1(CC / 128, MM / 128);
    gemm_bt<2><<<g1, 256, 0, stream>>>(og, Wo_b, x1, nullptr, x, nullptr, MM, CC, CC);

    // 7. LN2 -> z2; channel-mix combine
    lnz_kernel<<<MM, 256, 0, stream>>>(x1, ln2_w, ln2_b, z);
    mix2b_kernel<<<4096, 256, 0, stream>>>(z, cm_mix_k, cm_mix_r, xk, xr);

    // 8. kbuf2 = relu(xk @ cm_Wk^T)^2 bf16 ; sr = sigmoid(xr @ cm_Wr^T)
    gemm8<3><<<dim3(16, 16, 1), 512, 0, stream>>>(xk, cmWk_b, nullptr, kbuf2, MM, 4096, 1024, 1024);
    gemm_bt<4><<<g1, 256, 0, stream>>>(xr, cmWr_b, sr, nullptr, nullptr, nullptr, MM, CC, CC);

    // 9. split-K=4: partials[z] = kbuf2[:, z*1024:(z+1)*1024] @ cm_Wv[:, same]^T
    gemm8<7><<<dim3(4, 16, 4), 512, 0, stream>>>(kbuf2, cmWv_b, partials, nullptr, MM, 1024, 4096, 1024);

    // 10. out = x1 + sr * sum(partials)
    reduce_cmv<<<4096, 256, 0, stream>>>(partials, x1, sr, (float*)d_out);
}